// Round 1
// 111.199 us; speedup vs baseline: 1.0335x; 1.0335x over previous
//
#include <hip/hip_runtime.h>
#include <hip/hip_bf16.h>
#include <stdint.h>

#define BB 16
#define NN 2048
#define DD 64
#define BM 128    // queries per block: adjacent pair of rank tiles
#define BN 64
#define KSTR 72   // K/Vt LDS row stride in bf16 elems (144 B: 16B-aligned)
#define PSTR 72   // P LDS row stride

typedef __attribute__((ext_vector_type(8))) short short8;
typedef __attribute__((ext_vector_type(4))) float f32x4;

__device__ __forceinline__ unsigned short f2bf(float f) {   // RNE
  union { float f; uint32_t u; } c; c.f = f;
  uint32_t u = c.u + 0x7fffu + ((c.u >> 16) & 1u);
  return (unsigned short)(u >> 16);
}
__device__ __forceinline__ uint32_t pkrn(float a, float b) { // packed f32x2 -> bf16x2
  union { __hip_bfloat162 h; uint32_t u; } c;
  c.h = __float22bfloat162_rn(make_float2(a, b));
  return c.u;
}

#define QSCALE 0.18033688f   // 0.125 * log2(e): scores emerge in log2 units
#define CMW 1.0000010f       // exp(1e-6): masked-key weight (NOT zero)

// ---- fused pre-pass ----
// blocks [0,512):      K fp32->bf16 copy (4 float4/thread)
// blocks [512,1024):   V fp32 -> bf16 transposed vt[b][d][key] + fp32 tile sums
//                      tsum[b][t][d] = sum over keys in 64-tile t (V already in LDS)
// blocks [1024,1040):  per-batch counting sort of queries by valid
__global__ __launch_bounds__(256) void prep_kernel(const float* __restrict__ k,
                                                   const float* __restrict__ v,
                                                   const int* __restrict__ valid,
                                                   unsigned short* __restrict__ kbf,
                                                   unsigned short* __restrict__ vt,
                                                   int* __restrict__ perm,
                                                   int* __restrict__ sval,
                                                   float* __restrict__ tsum) {
  __shared__ float t[64][65];
  __shared__ int hist[2048];
  __shared__ int part[256];
  int id = blockIdx.x, tid = threadIdx.x;
  if (id < 512) {
#pragma unroll
    for (int r = 0; r < 4; r++) {
      int i = (id * 4 + r) * 256 + tid;      // 524288 float4s total
      float4 f = ((const float4*)k)[i];
      ushort4 o;
      o.x = f2bf(f.x); o.y = f2bf(f.y); o.z = f2bf(f.z); o.w = f2bf(f.w);
      ((ushort4*)kbf)[i] = o;
    }
  } else if (id < 1024) {
    int bid = id - 512;
    int b = bid >> 5;
    int k0 = (bid & 31) * 64;
    const float4* src = (const float4*)(v + ((size_t)b * NN + k0) * DD);
#pragma unroll
    for (int i = 0; i < 4; i++) {
      int f4 = tid + i * 256;
      int row = f4 >> 4, c4 = f4 & 15;
      float4 f = src[f4];
      t[row][c4*4+0] = f.x; t[row][c4*4+1] = f.y; t[row][c4*4+2] = f.z; t[row][c4*4+3] = f.w;
    }
    __syncthreads();
    int d = tid >> 2, kg = tid & 3;
    unsigned short* dst = vt + ((size_t)b * DD + d) * NN + k0 + kg * 16;
#pragma unroll
    for (int u = 0; u < 4; u++) {
      ushort4 o;
      o.x = f2bf(t[kg*16+u*4+0][d]);
      o.y = f2bf(t[kg*16+u*4+1][d]);
      o.z = f2bf(t[kg*16+u*4+2][d]);
      o.w = f2bf(t[kg*16+u*4+3][d]);
      ((ushort4*)dst)[u] = o;
    }
    // fp32 tile sum for the closed-form masked remainder (reads same LDS tile)
    if (tid < 64) {
      float s0 = 0.0f, s1 = 0.0f, s2 = 0.0f, s3 = 0.0f;
#pragma unroll 4
      for (int kk = 0; kk < 64; kk += 4) {
        s0 += t[kk+0][tid]; s1 += t[kk+1][tid];
        s2 += t[kk+2][tid]; s3 += t[kk+3][tid];
      }
      tsum[((size_t)b * 32 + (k0 >> 6)) * 64 + tid] = (s0 + s1) + (s2 + s3);
    }
  } else {
    // counting sort of queries by valid, ascending
    int b = id - 1024;
    for (int i = tid; i < 2048; i += 256) hist[i] = 0;
    __syncthreads();
    for (int i = tid; i < NN; i += 256) atomicAdd(&hist[valid[b * NN + i]], 1);
    __syncthreads();
    int base = tid * 8, loc[8], s = 0;
#pragma unroll
    for (int j = 0; j < 8; j++) { loc[j] = s; s += hist[base + j]; }
    part[tid] = s;
    __syncthreads();
    if (tid == 0) {
      int run = 0;
      for (int t2 = 0; t2 < 256; t2++) { int tmp = part[t2]; part[t2] = run; run += tmp; }
    }
    __syncthreads();
#pragma unroll
    for (int j = 0; j < 8; j++) hist[base + j] = part[tid] + loc[j];
    __syncthreads();
    for (int i = tid; i < NN; i += 256) {
      int vv = valid[b * NN + i];
      int pos = atomicAdd(&hist[vv], 1);
      perm[b * NN + pos] = i;
      sval[b * NN + pos] = vv;
    }
  }
}

// ---- main flash-attention ----
// Block = (batch, adjacent rank-tile PAIR u, parity split sp): 512 threads, 8 waves.
// Waves 0-3 own ranks [128u, 128u+64) (lighter half), waves 4-7 own
// [128u+64, 128u+128). Both halves share each staged K/V tile -> staging
// amortized over 128 queries; adjacent pairing keeps halves' key coverage
// nearly equal so skip waste is minimal. Split sp owns key tiles t==sp (mod NS).
// R7 semantics preserved: EVERY split block writes po/pz partials unconditionally.
template <int NS>
__global__ __launch_bounds__(512, 4) void attn_kernel(
    const float* __restrict__ q, const unsigned short* __restrict__ kbf,
    const unsigned short* __restrict__ vtbf, const int* __restrict__ perm,
    const int* __restrict__ sval, const float* __restrict__ tsum,
    float* __restrict__ out, unsigned short* __restrict__ po,
    float* __restrict__ pz)
{
  constexpr int NT = 32 / NS;   // key tiles per parity class

  __shared__ __align__(16) unsigned short Klds[BN * KSTR];
  __shared__ __align__(16) unsigned short Vlds[DD * KSTR];
  __shared__ __align__(16) unsigned short Plds[8 * 16 * PSTR];
  __shared__ int vld[BM];
  __shared__ int pidx[BM];

  // decode: id&7 = XCD; heavy pairs (large valid) dispatch first
  int id = blockIdx.x;
  int b = (id & 7) + 8 * ((id >> 3) & 1);
  int rest = id >> 4;                 // [0, 16*NS)
  int sp = rest % NS;
  int u = 15 - rest / NS;             // reversed: heavy pairs first
  int i0 = u * BM;                    // RANK base (sorted by valid)

  int tid = threadIdx.x;
  int w = tid >> 6, lane = tid & 63;
  int m = lane & 15, quad = lane >> 4;
  int h = w >> 2, wq = w & 3;         // half / wave-within-half
  int row = h * 64 + wq * 16 + m;     // rank offset within block

  if (tid < BM) {
    vld[tid]  = sval[b * NN + i0 + tid];
    pidx[tid] = perm[b * NN + i0 + tid];
  }
  // sorted ascending -> per-half max valid (wave-uniform)
  int Th = (sval[b * NN + i0 + h * 64 + 63] + 63) >> 6;   // this half's covered tiles
  int T1 = (sval[b * NN + i0 + 127] + 63) >> 6;           // block max (>= Th)
  int nh     = (Th - sp + NS - 1) / NS;   // tiles this wave computes (>=0)
  int nstage = (T1 - sp + NS - 1) / NS;   // tiles the block stages (>= nh)

  __syncthreads();

  f32x4 o[4] = {{0,0,0,0},{0,0,0,0},{0,0,0,0},{0,0,0,0}};
  float z = 0.0f;

  if (nstage > 0) {
    int vq = vld[row];
    int qrow = pidx[row];

    // Q fragment (B-operand layout), scale 0.125*log2e folded, fp32->bf16
    short8 qf[2];
    {
      const float* qp = q + ((size_t)b * NN + qrow) * DD;
#pragma unroll
      for (int s = 0; s < 2; s++) {
        float4 f0 = *(const float4*)(qp + s * 32 + quad * 8);
        float4 f1 = *(const float4*)(qp + s * 32 + quad * 8 + 4);
        union { short8 v; uint32_t x[4]; } tmp;
        tmp.x[0] = pkrn(f0.x * QSCALE, f0.y * QSCALE);
        tmp.x[1] = pkrn(f0.z * QSCALE, f0.w * QSCALE);
        tmp.x[2] = pkrn(f1.x * QSCALE, f1.y * QSCALE);
        tmp.x[3] = pkrn(f1.z * QSCALE, f1.w * QSCALE);
        qf[s] = tmp.v;
      }
    }

    unsigned short* pbase = Plds + w * 16 * PSTR;
    // staging: 512 threads x 16B each for K and V (one 64x64 bf16 tile each)
    int srow = tid >> 3, scol = (tid & 7) * 8;
    const unsigned short* gk = kbf + ((size_t)(b * NN + sp * BN + srow)) * DD + scol;
    const unsigned short* gv = vtbf + ((size_t)b * DD + srow) * NN + sp * BN + scol;

    uint4 ka = *(const uint4*)gk;
    uint4 va = *(const uint4*)gv;

    for (int it = 0; it < nstage; ++it) {
      int j0 = (sp + NS * it) * BN;
      __syncthreads();
      *(uint4*)&Klds[srow * KSTR + scol] = ka;
      *(uint4*)&Vlds[srow * KSTR + scol] = va;
      if (it + 1 < nstage) {
        gk += (size_t)NS * BN * DD; gv += NS * BN;
        ka = *(const uint4*)gk; va = *(const uint4*)gv;
      }
      __syncthreads();

      if (it < nh) {        // wave-uniform: light half skips fully-masked tiles
        // S^T = K . Q^T (scores in log2 units)
        f32x4 s[4] = {{0,0,0,0},{0,0,0,0},{0,0,0,0},{0,0,0,0}};
#pragma unroll
        for (int c = 0; c < 4; c++) {
#pragma unroll
          for (int ss = 0; ss < 2; ss++) {
            short8 kf = *(const short8*)&Klds[(c * 16 + m) * KSTR + ss * 32 + quad * 8];
            s[c] = __builtin_amdgcn_mfma_f32_16x16x32_bf16(kf, qf[ss], s[c], 0, 0, 0);
          }
        }

        // P: e^score = 2^(log2e*score); masked -> weight CMW
#pragma unroll
        for (int c = 0; c < 4; c++) {
          float e[4];
#pragma unroll
          for (int rr = 0; rr < 4; rr++) {
            int j = j0 + c * 16 + quad * 4 + rr;
            float ex = __builtin_amdgcn_exp2f(s[c][rr]);
            e[rr] = (j < vq) ? ex : CMW;
          }
          z += (e[0] + e[1]) + (e[2] + e[3]);
          *(uint2*)&pbase[m * PSTR + c * 16 + quad * 4] =
              make_uint2(pkrn(e[0], e[1]), pkrn(e[2], e[3]));
        }

        __builtin_amdgcn_s_waitcnt(0xc07f);  // lgkmcnt(0): wave-local P RAW

        // O^T = V^T . P^T
#pragma unroll
        for (int ss = 0; ss < 2; ss++) {
          short8 pf = *(const short8*)&pbase[m * PSTR + ss * 32 + quad * 8];
#pragma unroll
          for (int t = 0; t < 4; t++) {
            short8 vf = *(const short8*)&Vlds[(t * 16 + m) * KSTR + ss * 32 + quad * 8];
            o[t] = __builtin_amdgcn_mfma_f32_16x16x32_bf16(vf, pf, o[t], 0, 0, 0);
          }
        }
      }
    }
  }

  // z: sum over quads, then closed-form masked remainder of this parity class
  z += __shfl_xor(z, 16);
  z += __shfl_xor(z, 32);
  z += CMW * (float)((NT - nh) * 64);

  // O += CMW * sum of tile sums over this class's masked tiles (cache-hot)
  {
    const float* tb = tsum + (size_t)b * 32 * 64;
    for (int i = nh; i < NT; ++i) {
      const float* tr = tb + (sp + NS * i) * 64;
#pragma unroll
      for (int t = 0; t < 4; t++) {
        float4 a = *(const float4*)&tr[t * 16 + quad * 4];
        o[t][0] += CMW * a.x;
        o[t][1] += CMW * a.y;
        o[t][2] += CMW * a.z;
        o[t][3] += CMW * a.w;
      }
    }
  }

  if (NS > 1) {
    // partials in RANK space -> coalesced; combine scatters via perm
    int rrow = i0 + row;
    unsigned short* op = po + ((size_t)((sp * BB + b) * NN) + rrow) * DD;
#pragma unroll
    for (int t = 0; t < 4; t++)
      *(uint2*)&op[t * 16 + quad * 4] = make_uint2(pkrn(o[t][0], o[t][1]),
                                                   pkrn(o[t][2], o[t][3]));
    if (quad == 0) pz[(size_t)(sp * BB + b) * NN + rrow] = z;
  } else {
    float inv = 1.0f / z;
    int qrow = pidx[row];
    float* op2 = out + ((size_t)b * NN + qrow) * DD;
#pragma unroll
    for (int t = 0; t < 4; t++)
      *(float4*)&op2[t * 16 + quad * 4] =
          make_float4(o[t][0]*inv, o[t][1]*inv, o[t][2]*inv, o[t][3]*inv);
  }
}

// ---- combine (unchanged, R7-verified): out[perm[rank]] = sum_sp po / sum_sp pz ----
template <int NS>
__global__ __launch_bounds__(256) void combine_kernel(const unsigned short* __restrict__ po,
                                                      const float* __restrict__ pz,
                                                      const int* __restrict__ perm,
                                                      float* __restrict__ out) {
  int gid = blockIdx.x * 256 + threadIdx.x;   // 262144 threads x 8 elems
  size_t base = (size_t)gid * 8;
  int rowr = gid >> 3;                        // b*NN + rank
  float r[8] = {0,0,0,0,0,0,0,0};
  float zs = 0.0f;
#pragma unroll
  for (int sp = 0; sp < NS; sp++) {
    uint4 a = *(const uint4*)(po + (size_t)sp * BB * NN * DD + base);
    zs += pz[(size_t)sp * BB * NN + rowr];
    uint32_t aw[4] = {a.x, a.y, a.z, a.w};
#pragma unroll
    for (int i = 0; i < 4; i++) {
      r[2*i]   += __uint_as_float(aw[i] << 16);
      r[2*i+1] += __uint_as_float(aw[i] & 0xffff0000u);
    }
  }
  float inv = 1.0f / zs;
  int b = rowr >> 11;                         // NN = 2048
  int qrow = perm[rowr];
  float* op = out + ((size_t)(b * NN + qrow)) * DD + (gid & 7) * 8;
  *(float4*)&op[0] = make_float4(r[0]*inv, r[1]*inv, r[2]*inv, r[3]*inv);
  *(float4*)&op[4] = make_float4(r[4]*inv, r[5]*inv, r[6]*inv, r[7]*inv);
}

extern "C" void kernel_launch(void* const* d_in, const int* in_sizes, int n_in,
                              void* d_out, int out_size, void* d_ws, size_t ws_size,
                              hipStream_t stream) {
  const float* q = (const float*)d_in[0];
  const float* k = (const float*)d_in[1];
  const float* v = (const float*)d_in[2];
  const int* valid = (const int*)d_in[3];
  float* out = (float*)d_out;

  unsigned short* kbf  = (unsigned short*)d_ws;                    // 4 MB
  unsigned short* vtbf = kbf + (size_t)BB * NN * DD;               // 4 MB
  unsigned short* po   = vtbf + (size_t)BB * NN * DD;              // 4 x 4 MB bf16 partials
  float* pz   = (float*)(po + (size_t)4 * BB * NN * DD);           // 512 KB
  int*   perm = (int*)(pz + (size_t)4 * BB * NN);                  // 128 KB
  int*   sv   = perm + (size_t)BB * NN;                            // 128 KB
  float* tsum = (float*)(sv + (size_t)BB * NN);                    // 128 KB

  size_t need4 = ((char*)(tsum + (size_t)BB * 32 * DD)) - (char*)d_ws;

  hipLaunchKernelGGL(prep_kernel, dim3(1040), dim3(256), 0, stream,
                     k, v, valid, kbf, vtbf, perm, sv, tsum);
  if (ws_size >= need4) {
    hipLaunchKernelGGL((attn_kernel<4>), dim3(16 * 16 * 4), dim3(512), 0, stream,
                       q, kbf, vtbf, perm, sv, tsum, out, po, pz);
    hipLaunchKernelGGL((combine_kernel<4>), dim3(1024), dim3(256), 0, stream,
                       po, pz, perm, out);
  } else {
    hipLaunchKernelGGL((attn_kernel<1>), dim3(16 * 16), dim3(512), 0, stream,
                       q, kbf, vtbf, perm, sv, tsum, out, po, pz);
  }
}

// Round 2
// 109.827 us; speedup vs baseline: 1.0464x; 1.0125x over previous
//
#include <hip/hip_runtime.h>
#include <hip/hip_bf16.h>
#include <stdint.h>

#define BB 16
#define NN 2048
#define DD 64
#define BM 128    // queries per block: adjacent pair of rank tiles
#define BN 64
#define KSTR 72   // K/Vt LDS row stride in bf16 elems (144 B: 16B-aligned)
#define PSTR 72   // P LDS row stride

typedef __attribute__((ext_vector_type(8))) short short8;
typedef __attribute__((ext_vector_type(4))) float f32x4;
typedef __attribute__((ext_vector_type(2))) unsigned int uint32x2_t;
typedef __attribute__((ext_vector_type(4))) unsigned int uint32x4_t;

__device__ __forceinline__ unsigned short f2bf(float f) {   // RNE
  union { float f; uint32_t u; } c; c.f = f;
  uint32_t u = c.u + 0x7fffu + ((c.u >> 16) & 1u);
  return (unsigned short)(u >> 16);
}
__device__ __forceinline__ uint32_t pkrn(float a, float b) { // packed f32x2 -> bf16x2
  union { __hip_bfloat162 h; uint32_t u; } c;
  c.h = __float22bfloat162_rn(make_float2(a, b));
  return c.u;
}

#define QSCALE 0.18033688f   // 0.125 * log2(e): scores emerge in log2 units
#define CMW 1.0000010f       // exp(1e-6): masked-key weight (NOT zero)

// ---- fused pre-pass ----
// blocks [0,512):   V fp32 -> bf16 transposed vt[b][d][key] + fp32 tile sums
//                   tsum[b][t][d] = sum over keys in 64-tile t (V already in LDS)
// blocks [512,528): per-batch counting sort of queries by valid + zero cnt
// (K conversion is fused into attn staging; no kbf pass.)
__global__ __launch_bounds__(256) void prep_kernel(const float* __restrict__ v,
                                                   const int* __restrict__ valid,
                                                   unsigned short* __restrict__ vt,
                                                   int* __restrict__ perm,
                                                   int* __restrict__ sval,
                                                   float* __restrict__ tsum,
                                                   int* __restrict__ cnt) {
  __shared__ float t[64][65];
  __shared__ int hist[2048];
  __shared__ int part[256];
  int id = blockIdx.x, tid = threadIdx.x;
  if (id < 512) {
    int b = id >> 5;
    int k0 = (id & 31) * 64;
    const float4* src = (const float4*)(v + ((size_t)b * NN + k0) * DD);
#pragma unroll
    for (int i = 0; i < 4; i++) {
      int f4 = tid + i * 256;
      int row = f4 >> 4, c4 = f4 & 15;
      float4 f = src[f4];
      t[row][c4*4+0] = f.x; t[row][c4*4+1] = f.y; t[row][c4*4+2] = f.z; t[row][c4*4+3] = f.w;
    }
    __syncthreads();
    int d = tid >> 2, kg = tid & 3;
    unsigned short* dst = vt + ((size_t)b * DD + d) * NN + k0 + kg * 16;
#pragma unroll
    for (int u = 0; u < 4; u++) {
      ushort4 o;
      o.x = f2bf(t[kg*16+u*4+0][d]);
      o.y = f2bf(t[kg*16+u*4+1][d]);
      o.z = f2bf(t[kg*16+u*4+2][d]);
      o.w = f2bf(t[kg*16+u*4+3][d]);
      ((ushort4*)dst)[u] = o;
    }
    // fp32 tile sum for the closed-form masked remainder (reads same LDS tile)
    if (tid < 64) {
      float s0 = 0.0f, s1 = 0.0f, s2 = 0.0f, s3 = 0.0f;
#pragma unroll 4
      for (int kk = 0; kk < 64; kk += 4) {
        s0 += t[kk+0][tid]; s1 += t[kk+1][tid];
        s2 += t[kk+2][tid]; s3 += t[kk+3][tid];
      }
      tsum[((size_t)b * 32 + (k0 >> 6)) * 64 + tid] = (s0 + s1) + (s2 + s3);
    }
  } else {
    // counting sort of queries by valid, ascending (+ zero split counters)
    int b = id - 512;
    if (tid < 16) cnt[(b << 4) | tid] = 0;
    for (int i = tid; i < 2048; i += 256) hist[i] = 0;
    __syncthreads();
    for (int i = tid; i < NN; i += 256) atomicAdd(&hist[valid[b * NN + i]], 1);
    __syncthreads();
    int base = tid * 8, loc[8], s = 0;
#pragma unroll
    for (int j = 0; j < 8; j++) { loc[j] = s; s += hist[base + j]; }
    // parallel exclusive scan of per-thread totals (replaces tid0 serial loop)
    int lane6 = tid & 63, wv = tid >> 6;
    int val = s;
#pragma unroll
    for (int off = 1; off < 64; off <<= 1) {
      int n = __shfl_up(val, off);
      if (lane6 >= off) val += n;
    }
    if (lane6 == 63) part[wv] = val;   // wave totals in part[0..3]
    __syncthreads();
    int add = 0;
    for (int i = 0; i < wv; i++) add += part[i];
    int excl = (val - s) + add;
    __syncthreads();
#pragma unroll
    for (int j = 0; j < 8; j++) hist[base + j] = excl + loc[j];
    __syncthreads();
    for (int i = tid; i < NN; i += 256) {
      int vv = valid[b * NN + i];
      int pos = atomicAdd(&hist[vv], 1);
      perm[b * NN + pos] = i;
      sval[b * NN + pos] = vv;
    }
  }
}

// ---- main flash-attention, split-K with fused last-block combine ----
// Block = (batch, adjacent rank-tile PAIR u, parity split sp): 512 threads, 8 waves.
// K is staged directly from fp32 global with on-the-fly bf16 convert (no kbf).
// Every split block writes its po/pz partials with device-coherent (sc0 sc1)
// stores, waits vmcnt(0), then bumps a per-(b,u) counter; the LAST block
// re-reads all NS partials with coherent loads and writes out. R7 semantics
// (all splits always write) and R10 (cnt zeroed in prep) preserved.
template <int NS>
__global__ __launch_bounds__(512, 4) void attn_kernel(
    const float* __restrict__ q, const float* __restrict__ k,
    const unsigned short* __restrict__ vtbf, const int* __restrict__ perm,
    const int* __restrict__ sval, const float* __restrict__ tsum,
    float* __restrict__ out, unsigned short* __restrict__ po,
    float* __restrict__ pz, int* __restrict__ cnt)
{
  constexpr int NT = 32 / NS;   // key tiles per parity class

  __shared__ __align__(16) unsigned short Klds[BN * KSTR];
  __shared__ __align__(16) unsigned short Vlds[DD * KSTR];
  __shared__ __align__(16) unsigned short Plds[8 * 16 * PSTR];
  __shared__ int vld[BM];
  __shared__ int pidx[BM];
  __shared__ int lastFlag;

  // decode: id&7 = XCD; heavy pairs (large valid) dispatch first
  int id = blockIdx.x;
  int b = (id & 7) + 8 * ((id >> 3) & 1);
  int rest = id >> 4;                 // [0, 16*NS)
  int sp = rest % NS;
  int u = 15 - rest / NS;             // reversed: heavy pairs first
  int i0 = u * BM;                    // RANK base (sorted by valid)

  int tid = threadIdx.x;
  int w = tid >> 6, lane = tid & 63;
  int m = lane & 15, quad = lane >> 4;
  int h = w >> 2, wq = w & 3;         // half / wave-within-half
  int row = h * 64 + wq * 16 + m;     // rank offset within block

  if (tid < BM) {
    vld[tid]  = sval[b * NN + i0 + tid];
    pidx[tid] = perm[b * NN + i0 + tid];
  }
  // sorted ascending -> per-half max valid (wave-uniform)
  int Th = (sval[b * NN + i0 + h * 64 + 63] + 63) >> 6;   // this half's covered tiles
  int T1 = (sval[b * NN + i0 + 127] + 63) >> 6;           // block max (>= Th)
  int nh     = (Th - sp + NS - 1) / NS;   // tiles this wave computes (>=0)
  int nstage = (T1 - sp + NS - 1) / NS;   // tiles the block stages (>= nh)

  __syncthreads();

  f32x4 o[4] = {{0,0,0,0},{0,0,0,0},{0,0,0,0},{0,0,0,0}};
  float z = 0.0f;

  if (nstage > 0) {
    int vq = vld[row];
    int qrow = pidx[row];

    // Q fragment (B-operand layout), scale 0.125*log2e folded, fp32->bf16
    short8 qf[2];
    {
      const float* qp = q + ((size_t)b * NN + qrow) * DD;
#pragma unroll
      for (int s = 0; s < 2; s++) {
        float4 f0 = *(const float4*)(qp + s * 32 + quad * 8);
        float4 f1 = *(const float4*)(qp + s * 32 + quad * 8 + 4);
        union { short8 v; uint32_t x[4]; } tmp;
        tmp.x[0] = pkrn(f0.x * QSCALE, f0.y * QSCALE);
        tmp.x[1] = pkrn(f0.z * QSCALE, f0.w * QSCALE);
        tmp.x[2] = pkrn(f1.x * QSCALE, f1.y * QSCALE);
        tmp.x[3] = pkrn(f1.z * QSCALE, f1.w * QSCALE);
        qf[s] = tmp.v;
      }
    }

    unsigned short* pbase = Plds + w * 16 * PSTR;
    // staging: 512 threads; K read as fp32 (32B) + converted, V^T as bf16 (16B)
    int srow = tid >> 3, scol = (tid & 7) * 8;
    const float* gk = k + ((size_t)(b * NN + sp * BN + srow)) * DD + scol;
    const unsigned short* gv = vtbf + ((size_t)b * DD + srow) * NN + sp * BN + scol;

    float4 ka0 = *(const float4*)gk, ka1 = *(const float4*)(gk + 4);
    uint4 va = *(const uint4*)gv;

    for (int it = 0; it < nstage; ++it) {
      int j0 = (sp + NS * it) * BN;
      __syncthreads();
      *(uint4*)&Klds[srow * KSTR + scol] =
          make_uint4(pkrn(ka0.x, ka0.y), pkrn(ka0.z, ka0.w),
                     pkrn(ka1.x, ka1.y), pkrn(ka1.z, ka1.w));
      *(uint4*)&Vlds[srow * KSTR + scol] = va;
      if (it + 1 < nstage) {
        gk += (size_t)NS * BN * DD; gv += NS * BN;
        ka0 = *(const float4*)gk; ka1 = *(const float4*)(gk + 4);
        va = *(const uint4*)gv;
      }
      __syncthreads();

      if (it < nh) {        // wave-uniform: light half skips fully-masked tiles
        // S^T = K . Q^T (scores in log2 units)
        f32x4 s[4] = {{0,0,0,0},{0,0,0,0},{0,0,0,0},{0,0,0,0}};
#pragma unroll
        for (int c = 0; c < 4; c++) {
#pragma unroll
          for (int ss = 0; ss < 2; ss++) {
            short8 kf = *(const short8*)&Klds[(c * 16 + m) * KSTR + ss * 32 + quad * 8];
            s[c] = __builtin_amdgcn_mfma_f32_16x16x32_bf16(kf, qf[ss], s[c], 0, 0, 0);
          }
        }

        // P: e^score = 2^(log2e*score); masked -> weight CMW
#pragma unroll
        for (int c = 0; c < 4; c++) {
          float e[4];
#pragma unroll
          for (int rr = 0; rr < 4; rr++) {
            int j = j0 + c * 16 + quad * 4 + rr;
            float ex = __builtin_amdgcn_exp2f(s[c][rr]);
            e[rr] = (j < vq) ? ex : CMW;
          }
          z += (e[0] + e[1]) + (e[2] + e[3]);
          *(uint2*)&pbase[m * PSTR + c * 16 + quad * 4] =
              make_uint2(pkrn(e[0], e[1]), pkrn(e[2], e[3]));
        }

        __builtin_amdgcn_s_waitcnt(0xc07f);  // lgkmcnt(0): wave-local P RAW

        // O^T = V^T . P^T
#pragma unroll
        for (int ss = 0; ss < 2; ss++) {
          short8 pf = *(const short8*)&pbase[m * PSTR + ss * 32 + quad * 8];
#pragma unroll
          for (int t = 0; t < 4; t++) {
            short8 vf = *(const short8*)&Vlds[(t * 16 + m) * KSTR + ss * 32 + quad * 8];
            o[t] = __builtin_amdgcn_mfma_f32_16x16x32_bf16(vf, pf, o[t], 0, 0, 0);
          }
        }
      }
    }
  }

  // z: sum over quads, then closed-form masked remainder of this parity class
  z += __shfl_xor(z, 16);
  z += __shfl_xor(z, 32);
  z += CMW * (float)((NT - nh) * 64);

  // O += CMW * sum of tile sums over this class's masked tiles (cache-hot)
  {
    const float* tb = tsum + (size_t)b * 32 * 64;
    for (int i = nh; i < NT; ++i) {
      const float* tr = tb + (sp + NS * i) * 64;
#pragma unroll
      for (int t = 0; t < 4; t++) {
        float4 a = *(const float4*)&tr[t * 16 + quad * 4];
        o[t][0] += CMW * a.x;
        o[t][1] += CMW * a.y;
        o[t][2] += CMW * a.z;
        o[t][3] += CMW * a.w;
      }
    }
  }

  if (NS > 1) {
    // partials in RANK space, device-coherent stores (visible at LLC, no L2 dirty)
    int rrow = i0 + row;
    unsigned short* op = po + ((size_t)((sp * BB + b) * NN) + rrow) * DD;
#pragma unroll
    for (int t = 0; t < 4; t++) {
      uint32x2_t wv2 = {pkrn(o[t][0], o[t][1]), pkrn(o[t][2], o[t][3])};
      asm volatile("global_store_dwordx2 %0, %1, off sc0 sc1"
                   :: "v"(op + t * 16 + quad * 4), "v"(wv2) : "memory");
    }
    if (quad == 0) {
      float* pzp = pz + (size_t)(sp * BB + b) * NN + rrow;
      asm volatile("global_store_dword %0, %1, off sc0 sc1"
                   :: "v"(pzp), "v"(z) : "memory");
    }
    asm volatile("s_waitcnt vmcnt(0)" ::: "memory");
    __syncthreads();
    if (tid == 0) {
      int old = atomicAdd(&cnt[(b << 4) | u], 1);
      lastFlag = (old == NS - 1);
    }
    __syncthreads();
    if (lastFlag) {
      // last split of (b,u): combine all NS partials, write final rows
      for (int item = tid; item < BM * 8; item += 512) {
        int r = item >> 3, g = item & 7;
        int rrow2 = i0 + r;
        float acc[8] = {0,0,0,0,0,0,0,0};
        float zs = 0.0f;
        if constexpr (NS == 4) {
          const unsigned short* p0 = po + ((size_t)((0 * BB + b) * NN) + rrow2) * DD + g * 8;
          const unsigned short* p1 = po + ((size_t)((1 * BB + b) * NN) + rrow2) * DD + g * 8;
          const unsigned short* p2 = po + ((size_t)((2 * BB + b) * NN) + rrow2) * DD + g * 8;
          const unsigned short* p3 = po + ((size_t)((3 * BB + b) * NN) + rrow2) * DD + g * 8;
          const float* q0 = pz + (size_t)(0 * BB + b) * NN + rrow2;
          const float* q1 = pz + (size_t)(1 * BB + b) * NN + rrow2;
          const float* q2 = pz + (size_t)(2 * BB + b) * NN + rrow2;
          const float* q3 = pz + (size_t)(3 * BB + b) * NN + rrow2;
          uint32x4_t a0, a1, a2, a3; float z0, z1, z2, z3;
          asm volatile(
            "global_load_dwordx4 %0, %8, off sc0 sc1\n\t"
            "global_load_dwordx4 %1, %9, off sc0 sc1\n\t"
            "global_load_dwordx4 %2, %10, off sc0 sc1\n\t"
            "global_load_dwordx4 %3, %11, off sc0 sc1\n\t"
            "global_load_dword %4, %12, off sc0 sc1\n\t"
            "global_load_dword %5, %13, off sc0 sc1\n\t"
            "global_load_dword %6, %14, off sc0 sc1\n\t"
            "global_load_dword %7, %15, off sc0 sc1\n\t"
            "s_waitcnt vmcnt(0)"
            : "=&v"(a0), "=&v"(a1), "=&v"(a2), "=&v"(a3),
              "=&v"(z0), "=&v"(z1), "=&v"(z2), "=&v"(z3)
            : "v"(p0), "v"(p1), "v"(p2), "v"(p3),
              "v"(q0), "v"(q1), "v"(q2), "v"(q3)
            : "memory");
          zs = ((z0 + z1) + (z2 + z3));
          uint32_t aw[4][4] = {{a0.x, a0.y, a0.z, a0.w}, {a1.x, a1.y, a1.z, a1.w},
                               {a2.x, a2.y, a2.z, a2.w}, {a3.x, a3.y, a3.z, a3.w}};
#pragma unroll
          for (int s2 = 0; s2 < 4; s2++)
#pragma unroll
            for (int i = 0; i < 4; i++) {
              acc[2*i]   += __uint_as_float(aw[s2][i] << 16);
              acc[2*i+1] += __uint_as_float(aw[s2][i] & 0xffff0000u);
            }
        } else {
          for (int s2 = 0; s2 < NS; s2++) {
            const unsigned short* pp = po + ((size_t)((s2 * BB + b) * NN) + rrow2) * DD + g * 8;
            uint32x4_t a; float zv;
            asm volatile("global_load_dwordx4 %0, %2, off sc0 sc1\n\t"
                         "global_load_dword %1, %3, off sc0 sc1\n\t"
                         "s_waitcnt vmcnt(0)"
                         : "=&v"(a), "=&v"(zv)
                         : "v"(pp), "v"(pz + (size_t)(s2 * BB + b) * NN + rrow2)
                         : "memory");
            zs += zv;
            uint32_t aw[4] = {a.x, a.y, a.z, a.w};
#pragma unroll
            for (int i = 0; i < 4; i++) {
              acc[2*i]   += __uint_as_float(aw[i] << 16);
              acc[2*i+1] += __uint_as_float(aw[i] & 0xffff0000u);
            }
          }
        }
        float inv = 1.0f / zs;
        float* opf = out + ((size_t)b * NN + pidx[r]) * DD + g * 8;
        *(float4*)&opf[0] = make_float4(acc[0]*inv, acc[1]*inv, acc[2]*inv, acc[3]*inv);
        *(float4*)&opf[4] = make_float4(acc[4]*inv, acc[5]*inv, acc[6]*inv, acc[7]*inv);
      }
    }
  } else {
    float inv = 1.0f / z;
    int qrow = pidx[row];
    float* op2 = out + ((size_t)b * NN + qrow) * DD;
#pragma unroll
    for (int t = 0; t < 4; t++)
      *(float4*)&op2[t * 16 + quad * 4] =
          make_float4(o[t][0]*inv, o[t][1]*inv, o[t][2]*inv, o[t][3]*inv);
  }
}

extern "C" void kernel_launch(void* const* d_in, const int* in_sizes, int n_in,
                              void* d_out, int out_size, void* d_ws, size_t ws_size,
                              hipStream_t stream) {
  const float* q = (const float*)d_in[0];
  const float* k = (const float*)d_in[1];
  const float* v = (const float*)d_in[2];
  const int* valid = (const int*)d_in[3];
  float* out = (float*)d_out;

  unsigned short* vtbf = (unsigned short*)d_ws;                    // 4 MB
  int*   perm = (int*)(vtbf + (size_t)BB * NN * DD);               // 128 KB
  int*   sv   = perm + (size_t)BB * NN;                            // 128 KB
  float* tsum = (float*)(sv + (size_t)BB * NN);                    // 128 KB
  int*   cnt  = (int*)(tsum + (size_t)BB * 32 * DD);               // 1 KB
  float* pz   = (float*)(cnt + 256);                               // 512 KB
  unsigned short* po = (unsigned short*)(pz + (size_t)4 * BB * NN);// 16 MB

  size_t need4 = ((char*)(po + (size_t)4 * BB * NN * DD)) - (char*)d_ws;

  hipLaunchKernelGGL(prep_kernel, dim3(528), dim3(256), 0, stream,
                     v, valid, vtbf, perm, sv, tsum, cnt);
  if (ws_size >= need4) {
    hipLaunchKernelGGL((attn_kernel<4>), dim3(16 * 16 * 4), dim3(512), 0, stream,
                       q, k, vtbf, perm, sv, tsum, out, po, pz, cnt);
  } else {
    hipLaunchKernelGGL((attn_kernel<1>), dim3(16 * 16), dim3(512), 0, stream,
                       q, k, vtbf, perm, sv, tsum, out, po, pz, cnt);
  }
}

// Round 4
// 109.416 us; speedup vs baseline: 1.0504x; 1.0038x over previous
//
#include <hip/hip_runtime.h>
#include <hip/hip_bf16.h>
#include <stdint.h>

#define BB 16
#define NN 2048
#define DD 64
#define BM 128    // queries per block: adjacent pair of rank tiles
#define BN 64
#define KSTR 72   // K/Vt LDS row stride in bf16 elems (144 B: 16B-aligned)
#define PSTR 72   // P LDS row stride

typedef __attribute__((ext_vector_type(8))) short short8;
typedef __attribute__((ext_vector_type(4))) float f32x4;
typedef __attribute__((ext_vector_type(2))) unsigned int uint32x2_t;

__device__ __forceinline__ unsigned short f2bf(float f) {   // RNE
  union { float f; uint32_t u; } c; c.f = f;
  uint32_t u = c.u + 0x7fffu + ((c.u >> 16) & 1u);
  return (unsigned short)(u >> 16);
}
__device__ __forceinline__ uint32_t pkrn(float a, float b) { // packed f32x2 -> bf16x2
  union { __hip_bfloat162 h; uint32_t u; } c;
  c.h = __float22bfloat162_rn(make_float2(a, b));
  return c.u;
}

#define QSCALE 0.18033688f   // 0.125 * log2(e): scores emerge in log2 units
#define CMW 1.0000010f       // exp(1e-6): masked-key weight (NOT zero)

// ---- fused pre-pass ----
// blocks [0,16):    per-batch counting sort of queries by valid + zero cnt
//                   (dispatched first: longest latency chain)
// blocks [16,528):  V fp32 -> bf16 transposed vt[b][d][key] + fp32 tile sums
//                   tsum[b][t][d] = sum over keys in 64-tile t (V already in LDS)
__global__ __launch_bounds__(256) void prep_kernel(const float* __restrict__ v,
                                                   const int* __restrict__ valid,
                                                   unsigned short* __restrict__ vt,
                                                   int* __restrict__ perm,
                                                   int* __restrict__ sval,
                                                   float* __restrict__ tsum,
                                                   int* __restrict__ cnt) {
  __shared__ float t[64][65];
  __shared__ int hist[2048];
  __shared__ int part[256];
  int id = blockIdx.x, tid = threadIdx.x;
  if (id >= 16) {
    int bid = id - 16;
    int b = bid >> 5;
    int k0 = (bid & 31) * 64;
    const float4* src = (const float4*)(v + ((size_t)b * NN + k0) * DD);
#pragma unroll
    for (int i = 0; i < 4; i++) {
      int f4 = tid + i * 256;
      int row = f4 >> 4, c4 = f4 & 15;
      float4 f = src[f4];
      t[row][c4*4+0] = f.x; t[row][c4*4+1] = f.y; t[row][c4*4+2] = f.z; t[row][c4*4+3] = f.w;
    }
    __syncthreads();
    int d = tid >> 2, kg = tid & 3;
    unsigned short* dst = vt + ((size_t)b * DD + d) * NN + k0 + kg * 16;
#pragma unroll
    for (int u = 0; u < 4; u++) {
      ushort4 o;
      o.x = f2bf(t[kg*16+u*4+0][d]);
      o.y = f2bf(t[kg*16+u*4+1][d]);
      o.z = f2bf(t[kg*16+u*4+2][d]);
      o.w = f2bf(t[kg*16+u*4+3][d]);
      ((ushort4*)dst)[u] = o;
    }
    // fp32 tile sum for the closed-form masked remainder (reads same LDS tile)
    if (tid < 64) {
      float s0 = 0.0f, s1 = 0.0f, s2 = 0.0f, s3 = 0.0f;
#pragma unroll 4
      for (int kk = 0; kk < 64; kk += 4) {
        s0 += t[kk+0][tid]; s1 += t[kk+1][tid];
        s2 += t[kk+2][tid]; s3 += t[kk+3][tid];
      }
      tsum[((size_t)b * 32 + (k0 >> 6)) * 64 + tid] = (s0 + s1) + (s2 + s3);
    }
  } else {
    // counting sort of queries by valid, ascending (+ zero split counters)
    int b = id;
    if (tid < 16) cnt[(b << 4) | tid] = 0;
    for (int i = tid; i < 2048; i += 256) hist[i] = 0;
    __syncthreads();
    for (int i = tid; i < NN; i += 256) atomicAdd(&hist[valid[b * NN + i]], 1);
    __syncthreads();
    int base = tid * 8, loc[8], s = 0;
#pragma unroll
    for (int j = 0; j < 8; j++) { loc[j] = s; s += hist[base + j]; }
    // parallel exclusive scan of per-thread totals
    int lane6 = tid & 63, wv = tid >> 6;
    int val = s;
#pragma unroll
    for (int off = 1; off < 64; off <<= 1) {
      int n = __shfl_up(val, off);
      if (lane6 >= off) val += n;
    }
    if (lane6 == 63) part[wv] = val;   // wave totals in part[0..3]
    __syncthreads();
    int add = 0;
    for (int i = 0; i < wv; i++) add += part[i];
    int excl = (val - s) + add;
    __syncthreads();
#pragma unroll
    for (int j = 0; j < 8; j++) hist[base + j] = excl + loc[j];
    __syncthreads();
    for (int i = tid; i < NN; i += 256) {
      int vv = valid[b * NN + i];
      int pos = atomicAdd(&hist[vv], 1);
      perm[b * NN + pos] = i;
      sval[b * NN + pos] = vv;
    }
  }
}

// ---- main flash-attention, split-K with fused last-block combine ----
// Block = (batch, adjacent rank-tile PAIR u, parity split sp): 512 threads, 8 waves.
// NS=2: 512 blocks = exactly 2 blocks/CU, single dispatch round.
// K staged directly from fp32 global with on-the-fly bf16 convert.
// K/V LDS double-buffered: ONE barrier per tile (write next-buf, compute cur-buf;
// the previous iteration's barrier separates reads of a buffer from its overwrite).
// Every split block writes po/pz partials coherently (sc0 sc1), vmcnt(0), bumps
// per-(b,u) counter; last block folds the OTHER split's partials into its live
// fp32 accumulators and writes out. R7 (all splits always write) + R10 (cnt
// zeroed in prep) preserved.
template <int NS>
__global__ __launch_bounds__(512, 4) void attn_kernel(
    const float* __restrict__ q, const float* __restrict__ k,
    const unsigned short* __restrict__ vtbf, const int* __restrict__ perm,
    const int* __restrict__ sval, const float* __restrict__ tsum,
    float* __restrict__ out, unsigned short* __restrict__ po,
    float* __restrict__ pz, int* __restrict__ cnt)
{
  constexpr int NT = 32 / NS;   // key tiles per parity class

  __shared__ __align__(16) unsigned short Klds[2][BN * KSTR];
  __shared__ __align__(16) unsigned short Vlds[2][DD * KSTR];
  __shared__ __align__(16) unsigned short Plds[8 * 16 * PSTR];
  __shared__ int vld[BM];
  __shared__ int pidx[BM];
  __shared__ int lastFlag;

  // decode: id&7 = XCD; heavy pairs (large valid) dispatch first
  int id = blockIdx.x;
  int b = (id & 7) + 8 * ((id >> 3) & 1);
  int rest = id >> 4;                 // [0, 16*NS)
  int sp = rest % NS;
  int u = 15 - rest / NS;             // reversed: heavy pairs first
  int i0 = u * BM;                    // RANK base (sorted by valid)

  int tid = threadIdx.x;
  int w = tid >> 6, lane = tid & 63;
  int m = lane & 15, quad = lane >> 4;
  int h = w >> 2, wq = w & 3;         // half / wave-within-half
  int row = h * 64 + wq * 16 + m;     // rank offset within block

  if (tid < BM) {
    vld[tid]  = sval[b * NN + i0 + tid];
    pidx[tid] = perm[b * NN + i0 + tid];
  }
  // sorted ascending -> per-half max valid (wave-uniform)
  int Th = (sval[b * NN + i0 + h * 64 + 63] + 63) >> 6;   // this half's covered tiles
  int T1 = (sval[b * NN + i0 + 127] + 63) >> 6;           // block max (>= Th)
  int nh     = (Th - sp + NS - 1) / NS;   // tiles this wave computes (>=0)
  int nstage = (T1 - sp + NS - 1) / NS;   // tiles the block stages (>= nh)

  __syncthreads();

  f32x4 o[4] = {{0,0,0,0},{0,0,0,0},{0,0,0,0},{0,0,0,0}};
  float z = 0.0f;

  if (nstage > 0) {
    int vq = vld[row];
    int qrow = pidx[row];

    // Q fragment (B-operand layout), scale 0.125*log2e folded, fp32->bf16
    short8 qf[2];
    {
      const float* qp = q + ((size_t)b * NN + qrow) * DD;
#pragma unroll
      for (int s = 0; s < 2; s++) {
        float4 f0 = *(const float4*)(qp + s * 32 + quad * 8);
        float4 f1 = *(const float4*)(qp + s * 32 + quad * 8 + 4);
        union { short8 v; uint32_t x[4]; } tmp;
        tmp.x[0] = pkrn(f0.x * QSCALE, f0.y * QSCALE);
        tmp.x[1] = pkrn(f0.z * QSCALE, f0.w * QSCALE);
        tmp.x[2] = pkrn(f1.x * QSCALE, f1.y * QSCALE);
        tmp.x[3] = pkrn(f1.z * QSCALE, f1.w * QSCALE);
        qf[s] = tmp.v;
      }
    }

    unsigned short* pbase = Plds + w * 16 * PSTR;
    // staging: 512 threads; K read as fp32 (32B) + converted, V^T as bf16 (16B)
    int srow = tid >> 3, scol = (tid & 7) * 8;
    const float* gk = k + ((size_t)(b * NN + sp * BN + srow)) * DD + scol;
    const unsigned short* gv = vtbf + ((size_t)b * DD + srow) * NN + sp * BN + scol;

    float4 ka0 = *(const float4*)gk, ka1 = *(const float4*)(gk + 4);
    uint4 va = *(const uint4*)gv;

    // prologue: tile0 -> buf0; prefetch tile1 regs; one barrier
    *(uint4*)&Klds[0][srow * KSTR + scol] =
        make_uint4(pkrn(ka0.x, ka0.y), pkrn(ka0.z, ka0.w),
                   pkrn(ka1.x, ka1.y), pkrn(ka1.z, ka1.w));
    *(uint4*)&Vlds[0][srow * KSTR + scol] = va;
    if (nstage > 1) {
      gk += (size_t)NS * BN * DD; gv += NS * BN;
      ka0 = *(const float4*)gk; ka1 = *(const float4*)(gk + 4);
      va = *(const uint4*)gv;
    }
    __syncthreads();

    for (int it = 0; it < nstage; ++it) {
      int cur = it & 1;
      if (it + 1 < nstage) {
        // write tile it+1 into the other buffer (reads of it drained at the
        // previous barrier), then prefetch tile it+2 into registers
        int nxt = cur ^ 1;
        *(uint4*)&Klds[nxt][srow * KSTR + scol] =
            make_uint4(pkrn(ka0.x, ka0.y), pkrn(ka0.z, ka0.w),
                       pkrn(ka1.x, ka1.y), pkrn(ka1.z, ka1.w));
        *(uint4*)&Vlds[nxt][srow * KSTR + scol] = va;
        if (it + 2 < nstage) {
          gk += (size_t)NS * BN * DD; gv += NS * BN;
          ka0 = *(const float4*)gk; ka1 = *(const float4*)(gk + 4);
          va = *(const uint4*)gv;
        }
      }

      if (it < nh) {        // wave-uniform: light half skips fully-masked tiles
        int j0 = (sp + NS * it) * BN;
        // S^T = K . Q^T (scores in log2 units)
        f32x4 s[4] = {{0,0,0,0},{0,0,0,0},{0,0,0,0},{0,0,0,0}};
#pragma unroll
        for (int c = 0; c < 4; c++) {
#pragma unroll
          for (int ss = 0; ss < 2; ss++) {
            short8 kf = *(const short8*)&Klds[cur][(c * 16 + m) * KSTR + ss * 32 + quad * 8];
            s[c] = __builtin_amdgcn_mfma_f32_16x16x32_bf16(kf, qf[ss], s[c], 0, 0, 0);
          }
        }

        // P: e^score = 2^(log2e*score); masked -> weight CMW
#pragma unroll
        for (int c = 0; c < 4; c++) {
          float e[4];
#pragma unroll
          for (int rr = 0; rr < 4; rr++) {
            int j = j0 + c * 16 + quad * 4 + rr;
            float ex = __builtin_amdgcn_exp2f(s[c][rr]);
            e[rr] = (j < vq) ? ex : CMW;
          }
          z += (e[0] + e[1]) + (e[2] + e[3]);
          *(uint2*)&pbase[m * PSTR + c * 16 + quad * 4] =
              make_uint2(pkrn(e[0], e[1]), pkrn(e[2], e[3]));
        }

        __builtin_amdgcn_s_waitcnt(0xc07f);  // lgkmcnt(0): wave-local P RAW

        // O^T = V^T . P^T
#pragma unroll
        for (int ss = 0; ss < 2; ss++) {
          short8 pf = *(const short8*)&pbase[m * PSTR + ss * 32 + quad * 8];
#pragma unroll
          for (int t = 0; t < 4; t++) {
            short8 vf = *(const short8*)&Vlds[cur][(t * 16 + m) * KSTR + ss * 32 + quad * 8];
            o[t] = __builtin_amdgcn_mfma_f32_16x16x32_bf16(vf, pf, o[t], 0, 0, 0);
          }
        }
      }
      __syncthreads();   // buf[nxt] published; reads of buf[cur] drained
    }
  }

  // z: sum over quads, then closed-form masked remainder of this parity class
  z += __shfl_xor(z, 16);
  z += __shfl_xor(z, 32);
  z += CMW * (float)((NT - nh) * 64);

  // O += CMW * sum of tile sums over this class's masked tiles (cache-hot)
  {
    const float* tb = tsum + (size_t)b * 32 * 64;
    for (int i = nh; i < NT; ++i) {
      const float* tr = tb + (sp + NS * i) * 64;
#pragma unroll
      for (int t = 0; t < 4; t++) {
        float4 a = *(const float4*)&tr[t * 16 + quad * 4];
        o[t][0] += CMW * a.x;
        o[t][1] += CMW * a.y;
        o[t][2] += CMW * a.z;
        o[t][3] += CMW * a.w;
      }
    }
  }

  if (NS > 1) {
    // partials in RANK space, device-coherent stores
    int rrow = i0 + row;
    unsigned short* op = po + ((size_t)((sp * BB + b) * NN) + rrow) * DD + quad * 4;
#pragma unroll
    for (int t = 0; t < 4; t++) {
      uint32x2_t wv2 = {pkrn(o[t][0], o[t][1]), pkrn(o[t][2], o[t][3])};
      asm volatile("global_store_dwordx2 %0, %1, off sc0 sc1"
                   :: "v"(op + t * 16), "v"(wv2) : "memory");
    }
    if (quad == 0) {
      float* pzp = pz + (size_t)(sp * BB + b) * NN + rrow;
      asm volatile("global_store_dword %0, %1, off sc0 sc1"
                   :: "v"(pzp), "v"(z) : "memory");
    }
    asm volatile("s_waitcnt vmcnt(0)" ::: "memory");
    __syncthreads();
    if (tid == 0) {
      int old = atomicAdd(&cnt[(b << 4) | u], 1);
      lastFlag = (old == NS - 1);
    }
    __syncthreads();
    if (lastFlag) {
      // fold OTHER splits' bf16 partials into live fp32 accumulators
      float zs = z;
#pragma unroll
      for (int s2 = 0; s2 < NS; s2++) {
        if (s2 == sp) continue;
        const unsigned short* pp = po + ((size_t)((s2 * BB + b) * NN) + rrow) * DD + quad * 4;
        const float* pzp2 = pz + (size_t)(s2 * BB + b) * NN + rrow;
        uint32x2_t a0, a1, a2, a3; float zv;
        asm volatile(
          "global_load_dwordx2 %0, %5, off sc0 sc1\n\t"
          "global_load_dwordx2 %1, %6, off sc0 sc1\n\t"
          "global_load_dwordx2 %2, %7, off sc0 sc1\n\t"
          "global_load_dwordx2 %3, %8, off sc0 sc1\n\t"
          "global_load_dword %4, %9, off sc0 sc1\n\t"
          "s_waitcnt vmcnt(0)"
          : "=&v"(a0), "=&v"(a1), "=&v"(a2), "=&v"(a3), "=&v"(zv)
          : "v"(pp), "v"(pp + 16), "v"(pp + 32), "v"(pp + 48), "v"(pzp2)
          : "memory");
        zs += zv;
        uint32_t aw[4][2] = {{a0.x,a0.y},{a1.x,a1.y},{a2.x,a2.y},{a3.x,a3.y}};
#pragma unroll
        for (int t = 0; t < 4; t++) {
          o[t][0] += __uint_as_float(aw[t][0] << 16);
          o[t][1] += __uint_as_float(aw[t][0] & 0xffff0000u);
          o[t][2] += __uint_as_float(aw[t][1] << 16);
          o[t][3] += __uint_as_float(aw[t][1] & 0xffff0000u);
        }
      }
      float inv = 1.0f / zs;
      float* op2 = out + ((size_t)b * NN + pidx[row]) * DD + quad * 4;
#pragma unroll
      for (int t = 0; t < 4; t++)
        *(float4*)&op2[t * 16] =
            make_float4(o[t][0]*inv, o[t][1]*inv, o[t][2]*inv, o[t][3]*inv);
    }
  } else {
    float inv = 1.0f / z;
    int qrow = pidx[row];
    float* op2 = out + ((size_t)b * NN + qrow) * DD;
#pragma unroll
    for (int t = 0; t < 4; t++)
      *(float4*)&op2[t * 16 + quad * 4] =
          make_float4(o[t][0]*inv, o[t][1]*inv, o[t][2]*inv, o[t][3]*inv);
  }
}

extern "C" void kernel_launch(void* const* d_in, const int* in_sizes, int n_in,
                              void* d_out, int out_size, void* d_ws, size_t ws_size,
                              hipStream_t stream) {
  const float* q = (const float*)d_in[0];
  const float* k = (const float*)d_in[1];
  const float* v = (const float*)d_in[2];
  const int* valid = (const int*)d_in[3];
  float* out = (float*)d_out;

  unsigned short* vtbf = (unsigned short*)d_ws;                    // 4 MB
  int*   perm = (int*)(vtbf + (size_t)BB * NN * DD);               // 128 KB
  int*   sv   = perm + (size_t)BB * NN;                            // 128 KB
  float* tsum = (float*)(sv + (size_t)BB * NN);                    // 128 KB
  int*   cnt  = (int*)(tsum + (size_t)BB * 32 * DD);               // 1 KB
  float* pz   = (float*)(cnt + 256);                               // 256 KB
  unsigned short* po = (unsigned short*)(pz + (size_t)2 * BB * NN);// 8 MB

  size_t need2 = ((char*)(po + (size_t)2 * BB * NN * DD)) - (char*)d_ws;

  hipLaunchKernelGGL(prep_kernel, dim3(528), dim3(256), 0, stream,
                     v, valid, vtbf, perm, sv, tsum, cnt);
  if (ws_size >= need2) {
    hipLaunchKernelGGL((attn_kernel<2>), dim3(16 * 16 * 2), dim3(512), 0, stream,
                       q, k, vtbf, perm, sv, tsum, out, po, pz, cnt);
  } else {
    hipLaunchKernelGGL((attn_kernel<1>), dim3(16 * 16), dim3(512), 0, stream,
                       q, k, vtbf, perm, sv, tsum, out, po, pz, cnt);
  }
}